// Round 11
// baseline (79.141 us; speedup 1.0000x reference)
//
#include <hip/hip_runtime.h>

constexpr int NB = 4;
constexpr int CC = 128;
constexpr int HH = 64;
constexpr int WW = 64;
constexpr int HWp = HH * WW;      // 4096
constexpr int NHEADS = 4;
constexpr int K2 = 25;

typedef unsigned int   uint32;
typedef unsigned short ushort16;
typedef __attribute__((ext_vector_type(8))) short bf16x8;
typedef __attribute__((ext_vector_type(4))) float f32x4;

__device__ __forceinline__ ushort16 f2bf(float x) {
    uint32 b = __float_as_uint(x);
    return (ushort16)((b + 0x7FFFu + ((b >> 16) & 1u)) >> 16);   // RNE
}
__device__ __forceinline__ uint32 pack2(float lo, float hi) {
    return ((uint32)f2bf(hi) << 16) | (uint32)f2bf(lo);
}
__device__ __forceinline__ float bf_lo(uint32 u) { return __uint_as_float(u << 16); }
__device__ __forceinline__ float bf_hi(uint32 u) { return __uint_as_float(u & 0xFFFF0000u); }

// ---------------------------------------------------------------------------
// Kernel 0: convert Wq/Wk/Wv/Wfc fp32 -> bf16 (row-major preserved).
// ---------------------------------------------------------------------------
__global__ __launch_bounds__(256) void wconv_kernel(
    const float* __restrict__ Wq, const float* __restrict__ Wk,
    const float* __restrict__ Wv, const float* __restrict__ Wfc,
    ushort16* __restrict__ wbf)
{
    int i = blockIdx.x * 256 + threadIdx.x;   // 0..16383
    int m = i >> 12;
    int j = i & 4095;
    const float* s = (m == 0) ? Wq : ((m == 1) ? Wk : ((m == 2) ? Wv : Wfc));
    float4 f = reinterpret_cast<const float4*>(s)[j];
    uint32 w0 = pack2(f.x, f.y);
    uint32 w1 = pack2(f.z, f.w);
    uint32* d = reinterpret_cast<uint32*>(wbf + (size_t)m * 16384);
    d[j * 2]     = w0;
    d[j * 2 + 1] = w1;
}

// ---------------------------------------------------------------------------
// Kernel 1: MFMA projections. C[out=128][pix] = W[128x128] * X[c=128][pix].
// grid = 3 * NB * 64 = 768 blocks, 256 threads (2x2 wave grid).
// ---------------------------------------------------------------------------
__global__ __launch_bounds__(256) void proj_mfma(
    const float* __restrict__ q, const float* __restrict__ k, const float* __restrict__ v,
    const ushort16* __restrict__ wbf,
    ushort16* __restrict__ qp, ushort16* __restrict__ kp, ushort16* __restrict__ vp)
{
    __shared__ __align__(16) ushort16 lx[64 * 132];

    int blk = blockIdx.x;
    int p   = blk >> 8;
    int rem = blk & 255;
    int n   = rem >> 6;
    int pt  = rem & 63;
    int pix0 = pt * 64;

    const float*    X  = (p == 0) ? q  : ((p == 1) ? k  : v);
    ushort16*       O  = (p == 0) ? qp : ((p == 1) ? kp : vp);
    const ushort16* Wb = wbf + (size_t)p * 16384;
    const float*    Xb = X + (size_t)n * CC * HWp + pix0;

    int lane = threadIdx.x & 63;
    int cg   = threadIdx.x >> 6;

#pragma unroll
    for (int i = 0; i < 16; ++i) {
        int c0 = i * 8 + cg * 2;
        float a = Xb[c0 * HWp + lane];
        float b = Xb[(c0 + 1) * HWp + lane];
        *reinterpret_cast<uint32*>(&lx[lane * 132 + c0]) = pack2(a, b);
    }
    __syncthreads();

    int wid = threadIdx.x >> 6;
    int wr  = wid >> 1, wc = wid & 1;
    int p16 = lane & 15, kg = lane >> 4;

    f32x4 acc[4][2] = {};

#pragma unroll
    for (int k0 = 0; k0 < 128; k0 += 32) {
        bf16x8 A[4], B[2];
#pragma unroll
        for (int ai = 0; ai < 4; ++ai) {
            int o = wr * 64 + ai * 16 + p16;
            A[ai] = *reinterpret_cast<const bf16x8*>(&Wb[o * 128 + k0 + kg * 8]);
        }
#pragma unroll
        for (int bj = 0; bj < 2; ++bj) {
            int px = wc * 32 + bj * 16 + p16;
            const ushort16* sp = &lx[px * 132 + k0 + kg * 8];
            struct { unsigned long long lo, hi; } t;
            t.lo = *reinterpret_cast<const unsigned long long*>(sp);
            t.hi = *reinterpret_cast<const unsigned long long*>(sp + 4);
            B[bj] = __builtin_bit_cast(bf16x8, t);
        }
#pragma unroll
        for (int ai = 0; ai < 4; ++ai)
#pragma unroll
            for (int bj = 0; bj < 2; ++bj)
                acc[ai][bj] = __builtin_amdgcn_mfma_f32_16x16x32_bf16(
                    A[ai], B[bj], acc[ai][bj], 0, 0, 0);
    }

    ushort16* Ob = O + (size_t)(n * HWp + pix0) * CC;
#pragma unroll
    for (int ai = 0; ai < 4; ++ai) {
        int ob = wr * 64 + ai * 16 + kg * 4;
#pragma unroll
        for (int bj = 0; bj < 2; ++bj) {
            int px = wc * 32 + bj * 16 + p16;
            uint32* dst = reinterpret_cast<uint32*>(&Ob[(size_t)px * CC + ob]);
            dst[0] = pack2(acc[ai][bj][0], acc[ai][bj][1]);
            dst[1] = pack2(acc[ai][bj][2], acc[ai][bj][3]);
        }
    }
}

// ---------------------------------------------------------------------------
// Kernel 2: fused flow sampling + multi-head attention, 512B-segment gathers.
// 64-thread blocks = 1 wave = 2 pixels. Lane = (px[1], h[1], c[4]):
// px = lane>>5, h = (lane>>4)&1 (tap parity), c = lane&15 (8-ch chunk).
// Each load instr covers taps {2k, 2k+1} of both pixels: 2 x 512B contiguous
// segments (vs 4 x 256B before) -> half the TA segment work.
// Tap-parity halves exchange dot products via shfl_xor(.,16).
// oh written IN-PLACE over qp.
// ---------------------------------------------------------------------------

#define KVLOAD2(BUF, BASE, R) { \
    const ushort16* r_ = (BASE) + roff[R]; \
    _Pragma("unroll") \
    for (int kq = 0; kq < 3; ++kq) \
        BUF[kq] = *reinterpret_cast<const uint4*>(r_ + coffL[kq]); }

#define DOT8(U) \
    fmaf(qv[7], bf_hi((U).w), fmaf(qv[6], bf_lo((U).w), \
    fmaf(qv[5], bf_hi((U).z), fmaf(qv[4], bf_lo((U).z), \
    fmaf(qv[3], bf_hi((U).y), fmaf(qv[2], bf_lo((U).y), \
    fmaf(qv[1], bf_hi((U).x), qv[0] * bf_lo((U).x))))))))

#define KC2(BUF, R) { \
    float do_[3], ds_[3]; \
    _Pragma("unroll") \
    for (int kq = 0; kq < 3; ++kq) do_[kq] = DOT8(BUF[kq]); \
    _Pragma("unroll") \
    for (int kq = 0; kq < 3; ++kq) ds_[kq] = __shfl_xor(do_[kq], 16); \
    float pd_[6]; \
    _Pragma("unroll") \
    for (int kq = 0; kq < 3; ++kq) { \
        pd_[2 * kq]     = hsel ? ds_[kq] : do_[kq]; \
        pd_[2 * kq + 1] = hsel ? do_[kq] : ds_[kq]; \
    } \
    float hbr_[5]; \
    _Pragma("unroll") \
    for (int kx = 0; kx < 5; ++kx) \
        hbr_[kx] = pd_[kx] * XA[kx] + pd_[kx + 1] * XB[kx + 1]; \
    if ((R) < 5) { \
        _Pragma("unroll") \
        for (int kx = 0; kx < 5; ++kx) l[(R) * 5 + kx] = hbr_[kx] * YT[R]; } \
    if ((R) >= 1) { \
        _Pragma("unroll") \
        for (int kx = 0; kx < 5; ++kx) \
            l[((R) - 1) * 5 + kx] = fmaf(hbr_[kx], YB[R], l[((R) - 1) * 5 + kx]); } }

#define VC2(BUF, R) { \
    float lhc_[6]; \
    if ((R) < 5) { \
        lhc_[0] = l[(R) * 5 + 0] * XA[0]; \
        _Pragma("unroll") \
        for (int rx = 1; rx < 5; ++rx) \
            lhc_[rx] = l[(R) * 5 + rx] * XA[rx] + l[(R) * 5 + rx - 1] * XB[rx]; \
        lhc_[5] = l[(R) * 5 + 4] * XB[5]; \
    } else { \
        _Pragma("unroll") \
        for (int rx = 0; rx < 6; ++rx) lhc_[rx] = 0.f; \
    } \
    _Pragma("unroll") \
    for (int kq = 0; kq < 3; ++kq) { \
        float lc_ = hsel ? lhc_[2 * kq + 1] : lhc_[2 * kq]; \
        float lp_ = hsel ? lhp[2 * kq + 1] : lhp[2 * kq]; \
        float w6_ = lc_ * YT[R] + lp_ * YB[R]; \
        uint4 u_ = BUF[kq]; \
        acc[0] = fmaf(bf_lo(u_.x), w6_, acc[0]); \
        acc[1] = fmaf(bf_hi(u_.x), w6_, acc[1]); \
        acc[2] = fmaf(bf_lo(u_.y), w6_, acc[2]); \
        acc[3] = fmaf(bf_hi(u_.y), w6_, acc[3]); \
        acc[4] = fmaf(bf_lo(u_.z), w6_, acc[4]); \
        acc[5] = fmaf(bf_hi(u_.z), w6_, acc[5]); \
        acc[6] = fmaf(bf_lo(u_.w), w6_, acc[6]); \
        acc[7] = fmaf(bf_hi(u_.w), w6_, acc[7]); \
    } \
    _Pragma("unroll") \
    for (int rx = 0; rx < 6; ++rx) lhp[rx] = lhc_[rx]; }

__global__ __launch_bounds__(64) void attn_kernel(
    ushort16* qoh,
    const ushort16* __restrict__ kp, const ushort16* __restrict__ vp,
    const float* __restrict__ flow,
    float* __restrict__ attn)
{
    int blk = blockIdx.x;                        // 0..8191
    int swz = ((blk & 7) << 10) + (blk >> 3);    // XCD-contiguous bands
    int lane = threadIdx.x;                      // 0..63
    int px   = lane >> 5;                        // pixel within wave
    bool hsel = (lane & 16) != 0;                // tap parity
    int h    = hsel ? 1 : 0;
    int c    = lane & 15;                        // 8-channel chunk
    int pix  = swz * 2 + px;                     // global pixel 0..16383
    int n    = pix >> 12;
    int yx   = pix & 4095;
    int y    = yx >> 6, x = yx & 63;

    float fx = flow[((size_t)n * 2 + 0) * HWp + yx];
    float fy = flow[((size_t)n * 2 + 1) * HWp + yx];
    float pxf = (float)x + fx, pyf = (float)y + fy;
    float X0 = floorf(pxf), Y0 = floorf(pyf);
    float wx = pxf - X0,    wy = pyf - Y0;
    int ix0 = (int)X0 - 2,  iy0 = (int)Y0 - 2;

    int roff[6];
    float XA[6], XB[6], YT[6], YB[6];
#pragma unroll
    for (int r = 0; r < 6; ++r) {
        int xi = ix0 + r;
        float mx = (xi >= 0 && xi < WW) ? 1.f : 0.f;
        XA[r] = (1.f - wx) * mx;
        XB[r] = wx * mx;
        int yi = iy0 + r;
        float my = (yi >= 0 && yi < HH) ? 1.f : 0.f;
        int yc = yi < 0 ? 0 : (yi > HH - 1 ? HH - 1 : yi);
        roff[r] = yc * (WW * CC);
        YT[r] = (1.f - wy) * my;
        YB[r] = wy * my;
    }
    // this lane's 3 taps: t = 2k + h
    int coffL[3];
#pragma unroll
    for (int kq = 0; kq < 3; ++kq) {
        int xi = ix0 + 2 * kq + h;
        int xc = xi < 0 ? 0 : (xi > WW - 1 ? WW - 1 : xi);
        coffL[kq] = xc * CC + c * 8;
    }

    const ushort16* kb  = kp + (size_t)n * HWp * CC;
    const ushort16* vbp = vp + (size_t)n * HWp * CC;
    ushort16* qb = qoh + (size_t)pix * CC + c * 8;

    uint4 qraw = *reinterpret_cast<const uint4*>(qb);
    float qv[8] = { bf_lo(qraw.x), bf_hi(qraw.x), bf_lo(qraw.y), bf_hi(qraw.y),
                    bf_lo(qraw.z), bf_hi(qraw.z), bf_lo(qraw.w), bf_hi(qraw.w) };

    // ---- K pass: 2-row register pipeline, 512B-segment loads ----
    float l[25];
    {
        uint4 kA[3], kB[3];
        KVLOAD2(kA, kb, 0)
        KVLOAD2(kB, kb, 1)
        KC2(kA, 0)
        KVLOAD2(kA, kb, 2)
        KC2(kB, 1)
        KVLOAD2(kB, kb, 3)
        KC2(kA, 2)
        KVLOAD2(kA, kb, 4)
        KC2(kB, 3)
        KVLOAD2(kB, kb, 5)
        KC2(kA, 4)
        KC2(kB, 5)
    }

    // ---- V prologue: issued before softmax so latency hides under VALU ----
    uint4 vA[3], vB[3];
    KVLOAD2(vA, vbp, 0)
    KVLOAD2(vB, vbp, 1)

    // ---- reduce over the head's 4 chunk-lanes (=32 channels) ----
#pragma unroll
    for (int kk = 0; kk < 25; ++kk) {
        float s = l[kk];
        s += __shfl_xor(s, 1);
        s += __shfl_xor(s, 2);
        l[kk] = s * 0.17677669529663687f;   // 1/sqrt(32)
    }

    // ---- softmax over 25 ----
    float m = l[0];
#pragma unroll
    for (int kk = 1; kk < 25; ++kk) m = fmaxf(m, l[kk]);
    float sum = 0.f;
#pragma unroll
    for (int kk = 0; kk < 25; ++kk) { l[kk] = __expf(l[kk] - m); sum += l[kk]; }
    float inv = 1.f / sum;
#pragma unroll
    for (int kk = 0; kk < 25; ++kk) l[kk] *= inv;

    // ---- V pass: 2-row register pipeline ----
    float acc[8] = {0.f, 0.f, 0.f, 0.f, 0.f, 0.f, 0.f, 0.f};
    float lhp[6] = {0.f, 0.f, 0.f, 0.f, 0.f, 0.f};
    VC2(vA, 0)
    KVLOAD2(vA, vbp, 2)
    VC2(vB, 1)
    KVLOAD2(vB, vbp, 3)
    VC2(vA, 2)
    KVLOAD2(vA, vbp, 4)
    VC2(vB, 3)
    KVLOAD2(vB, vbp, 5)
    VC2(vA, 4)
    VC2(vB, 5)

    // combine tap-parity halves of the V accumulation
#pragma unroll
    for (int i = 0; i < 8; ++i) acc[i] += __shfl_xor(acc[i], 16);

    // ---- stores last: attn (fp32, reference layout) then oh in-place ----
    {
        int head = c >> 2, j = c & 3;
        float* ab = attn + (((size_t)n * NHEADS + head) * K2) * HWp + yx;
#pragma unroll
        for (int kk = 0; kk < 25; ++kk)
            if (!hsel && (kk & 3) == j) ab[(size_t)kk * HWp] = l[kk];
    }

    if (!hsel) {
        uint4 o;
        o.x = pack2(acc[0], acc[1]);
        o.y = pack2(acc[2], acc[3]);
        o.z = pack2(acc[4], acc[5]);
        o.w = pack2(acc[6], acc[7]);
        *reinterpret_cast<uint4*>(qb) = o;     // oh, in-place over qp
    }
}

// ---------------------------------------------------------------------------
// Kernel 3: MFMA final projection. out[o][pix] = Wfc * oh[pix][c]^T.
// ---------------------------------------------------------------------------
__global__ __launch_bounds__(256) void fc_mfma(
    const ushort16* __restrict__ oh, const ushort16* __restrict__ wfcb,
    float* __restrict__ out)
{
    int blk = blockIdx.x;
    int gp0 = blk * 64;
    int n   = gp0 >> 12;
    int yx0 = gp0 & 4095;

    int lane = threadIdx.x & 63;
    int wid  = threadIdx.x >> 6;
    int wr = wid >> 1, wc = wid & 1;
    int p16 = lane & 15, kg = lane >> 4;

    const ushort16* ohb = oh + (size_t)gp0 * CC;

    f32x4 acc[4][2] = {};

#pragma unroll
    for (int k0 = 0; k0 < 128; k0 += 32) {
        bf16x8 A[4], B[2];
#pragma unroll
        for (int ai = 0; ai < 4; ++ai) {
            int o = wr * 64 + ai * 16 + p16;
            A[ai] = *reinterpret_cast<const bf16x8*>(&wfcb[o * 128 + k0 + kg * 8]);
        }
#pragma unroll
        for (int bj = 0; bj < 2; ++bj) {
            int px = wc * 32 + bj * 16 + p16;
            B[bj] = *reinterpret_cast<const bf16x8*>(&ohb[(size_t)px * CC + k0 + kg * 8]);
        }
#pragma unroll
        for (int ai = 0; ai < 4; ++ai)
#pragma unroll
            for (int bj = 0; bj < 2; ++bj)
                acc[ai][bj] = __builtin_amdgcn_mfma_f32_16x16x32_bf16(
                    A[ai], B[bj], acc[ai][bj], 0, 0, 0);
    }

    float* ob = out + (size_t)n * CC * HWp + yx0;
#pragma unroll
    for (int ai = 0; ai < 4; ++ai) {
        int o = wr * 64 + ai * 16 + kg * 4;
#pragma unroll
        for (int bj = 0; bj < 2; ++bj) {
            int px = wc * 32 + bj * 16 + p16;
#pragma unroll
            for (int r = 0; r < 4; ++r)
                ob[(size_t)(o + r) * HWp + px] = acc[ai][bj][r];
        }
    }
}

// ---------------------------------------------------------------------------
extern "C" void kernel_launch(void* const* d_in, const int* in_sizes, int n_in,
                              void* d_out, int out_size, void* d_ws, size_t ws_size,
                              hipStream_t stream)
{
    const float* q    = (const float*)d_in[0];
    const float* k    = (const float*)d_in[1];
    const float* v    = (const float*)d_in[2];
    const float* flow = (const float*)d_in[3];
    const float* Wq   = (const float*)d_in[4];
    const float* Wk   = (const float*)d_in[5];
    const float* Wv   = (const float*)d_in[6];
    const float* Wfc  = (const float*)d_in[7];

    float* out  = (float*)d_out;                          // [N][C][H][W]
    float* attn = out + (size_t)NB * CC * HWp;            // [N][NHEADS][K2][H][W]

    ushort16* ws = (ushort16*)d_ws;
    size_t slab = (size_t)NB * HWp * CC;
    ushort16* qp  = ws;                                   // q -> oh in-place
    ushort16* kp  = ws + slab;
    ushort16* vp  = ws + 2 * slab;
    ushort16* wbf = ws + 3 * slab;

    wconv_kernel<<<dim3(64), dim3(256), 0, stream>>>(Wq, Wk, Wv, Wfc, wbf);
    proj_mfma<<<dim3(768), dim3(256), 0, stream>>>(q, k, v, wbf, qp, kp, vp);
    attn_kernel<<<dim3(8192), dim3(64), 0, stream>>>(qp, kp, vp, flow, attn);
    fc_mfma<<<dim3(256), dim3(256), 0, stream>>>(qp, wbf + 3 * 16384, out);
}

// Round 12
// 50.509 us; speedup vs baseline: 1.5669x; 1.5669x over previous
//
#include <hip/hip_runtime.h>

constexpr int NB = 4;
constexpr int CC = 128;
constexpr int HH = 64;
constexpr int WW = 64;
constexpr int HWp = HH * WW;      // 4096
constexpr int NHEADS = 4;
constexpr int K2 = 25;

typedef unsigned int   uint32;
typedef unsigned short ushort16;
typedef __attribute__((ext_vector_type(8))) short bf16x8;
typedef __attribute__((ext_vector_type(4))) float f32x4;

__device__ __forceinline__ ushort16 f2bf(float x) {
    uint32 b = __float_as_uint(x);
    return (ushort16)((b + 0x7FFFu + ((b >> 16) & 1u)) >> 16);   // RNE
}
__device__ __forceinline__ uint32 pack2(float lo, float hi) {
    return ((uint32)f2bf(hi) << 16) | (uint32)f2bf(lo);
}
__device__ __forceinline__ float bf_lo(uint32 u) { return __uint_as_float(u << 16); }
__device__ __forceinline__ float bf_hi(uint32 u) { return __uint_as_float(u & 0xFFFF0000u); }

// ---------------------------------------------------------------------------
// Kernel 0: convert Wq/Wk/Wv/Wfc fp32 -> bf16 (row-major preserved).
// ---------------------------------------------------------------------------
__global__ __launch_bounds__(256) void wconv_kernel(
    const float* __restrict__ Wq, const float* __restrict__ Wk,
    const float* __restrict__ Wv, const float* __restrict__ Wfc,
    ushort16* __restrict__ wbf)
{
    int i = blockIdx.x * 256 + threadIdx.x;   // 0..16383
    int m = i >> 12;
    int j = i & 4095;
    const float* s = (m == 0) ? Wq : ((m == 1) ? Wk : ((m == 2) ? Wv : Wfc));
    float4 f = reinterpret_cast<const float4*>(s)[j];
    uint32 w0 = pack2(f.x, f.y);
    uint32 w1 = pack2(f.z, f.w);
    uint32* d = reinterpret_cast<uint32*>(wbf + (size_t)m * 16384);
    d[j * 2]     = w0;
    d[j * 2 + 1] = w1;
}

// ---------------------------------------------------------------------------
// Kernel 1: MFMA projections. C[out=128][pix] = W[128x128] * X[c=128][pix].
// grid = 3 * NB * 64 = 768 blocks, 256 threads (2x2 wave grid).
// ---------------------------------------------------------------------------
__global__ __launch_bounds__(256) void proj_mfma(
    const float* __restrict__ q, const float* __restrict__ k, const float* __restrict__ v,
    const ushort16* __restrict__ wbf,
    ushort16* __restrict__ qp, ushort16* __restrict__ kp, ushort16* __restrict__ vp)
{
    __shared__ __align__(16) ushort16 lx[64 * 132];

    int blk = blockIdx.x;
    int p   = blk >> 8;
    int rem = blk & 255;
    int n   = rem >> 6;
    int pt  = rem & 63;
    int pix0 = pt * 64;

    const float*    X  = (p == 0) ? q  : ((p == 1) ? k  : v);
    ushort16*       O  = (p == 0) ? qp : ((p == 1) ? kp : vp);
    const ushort16* Wb = wbf + (size_t)p * 16384;
    const float*    Xb = X + (size_t)n * CC * HWp + pix0;

    int lane = threadIdx.x & 63;
    int cg   = threadIdx.x >> 6;

#pragma unroll
    for (int i = 0; i < 16; ++i) {
        int c0 = i * 8 + cg * 2;
        float a = Xb[c0 * HWp + lane];
        float b = Xb[(c0 + 1) * HWp + lane];
        *reinterpret_cast<uint32*>(&lx[lane * 132 + c0]) = pack2(a, b);
    }
    __syncthreads();

    int wid = threadIdx.x >> 6;
    int wr  = wid >> 1, wc = wid & 1;
    int p16 = lane & 15, kg = lane >> 4;

    f32x4 acc[4][2] = {};

#pragma unroll
    for (int k0 = 0; k0 < 128; k0 += 32) {
        bf16x8 A[4], B[2];
#pragma unroll
        for (int ai = 0; ai < 4; ++ai) {
            int o = wr * 64 + ai * 16 + p16;
            A[ai] = *reinterpret_cast<const bf16x8*>(&Wb[o * 128 + k0 + kg * 8]);
        }
#pragma unroll
        for (int bj = 0; bj < 2; ++bj) {
            int px = wc * 32 + bj * 16 + p16;
            const ushort16* sp = &lx[px * 132 + k0 + kg * 8];
            struct { unsigned long long lo, hi; } t;
            t.lo = *reinterpret_cast<const unsigned long long*>(sp);
            t.hi = *reinterpret_cast<const unsigned long long*>(sp + 4);
            B[bj] = __builtin_bit_cast(bf16x8, t);
        }
#pragma unroll
        for (int ai = 0; ai < 4; ++ai)
#pragma unroll
            for (int bj = 0; bj < 2; ++bj)
                acc[ai][bj] = __builtin_amdgcn_mfma_f32_16x16x32_bf16(
                    A[ai], B[bj], acc[ai][bj], 0, 0, 0);
    }

    ushort16* Ob = O + (size_t)(n * HWp + pix0) * CC;
#pragma unroll
    for (int ai = 0; ai < 4; ++ai) {
        int ob = wr * 64 + ai * 16 + kg * 4;
#pragma unroll
        for (int bj = 0; bj < 2; ++bj) {
            int px = wc * 32 + bj * 16 + p16;
            uint32* dst = reinterpret_cast<uint32*>(&Ob[(size_t)px * CC + ob]);
            dst[0] = pack2(acc[ai][bj][0], acc[ai][bj][1]);
            dst[1] = pack2(acc[ai][bj][2], acc[ai][bj][3]);
        }
    }
}

// ---------------------------------------------------------------------------
// Kernel 2: fused flow sampling + multi-head attention, software-pipelined.
// 64-thread blocks (1 wave = 4 pixels, 16 lanes/pixel, 8 ch/lane).
// grid = 4096. oh written IN-PLACE into the qp slab.
// ---------------------------------------------------------------------------

#define KVLOAD(BUF, BASE, R) { \
    const ushort16* r_ = (BASE) + roff[R]; \
    _Pragma("unroll") \
    for (int rx = 0; rx < 6; ++rx) \
        BUF[rx] = *reinterpret_cast<const uint4*>(r_ + coff[rx]); }

#define DOT8(U) \
    fmaf(qv[7], bf_hi((U).w), fmaf(qv[6], bf_lo((U).w), \
    fmaf(qv[5], bf_hi((U).z), fmaf(qv[4], bf_lo((U).z), \
    fmaf(qv[3], bf_hi((U).y), fmaf(qv[2], bf_lo((U).y), \
    fmaf(qv[1], bf_hi((U).x), qv[0] * bf_lo((U).x))))))))

#define KCONSUME(BUF, R) { \
    float pd_[6]; \
    _Pragma("unroll") \
    for (int rx = 0; rx < 6; ++rx) pd_[rx] = DOT8(BUF[rx]); \
    float hbr_[5]; \
    _Pragma("unroll") \
    for (int kx = 0; kx < 5; ++kx) \
        hbr_[kx] = pd_[kx] * XA[kx] + pd_[kx + 1] * XB[kx + 1]; \
    if ((R) < 5) { \
        _Pragma("unroll") \
        for (int kx = 0; kx < 5; ++kx) l[(R) * 5 + kx] = hbr_[kx] * YT[R]; } \
    if ((R) >= 1) { \
        _Pragma("unroll") \
        for (int kx = 0; kx < 5; ++kx) \
            l[((R) - 1) * 5 + kx] = fmaf(hbr_[kx], YB[R], l[((R) - 1) * 5 + kx]); } }

#define VCONSUME(BUF, R) { \
    float lhc_[6]; \
    if ((R) < 5) { \
        lhc_[0] = l[(R) * 5 + 0] * XA[0]; \
        _Pragma("unroll") \
        for (int rx = 1; rx < 5; ++rx) \
            lhc_[rx] = l[(R) * 5 + rx] * XA[rx] + l[(R) * 5 + rx - 1] * XB[rx]; \
        lhc_[5] = l[(R) * 5 + 4] * XB[5]; \
    } else { \
        _Pragma("unroll") \
        for (int rx = 0; rx < 6; ++rx) lhc_[rx] = 0.f; \
    } \
    _Pragma("unroll") \
    for (int rx = 0; rx < 6; ++rx) { \
        float w6_ = lhc_[rx] * YT[R] + lhp[rx] * YB[R]; \
        uint4 u_ = BUF[rx]; \
        acc[0] = fmaf(bf_lo(u_.x), w6_, acc[0]); \
        acc[1] = fmaf(bf_hi(u_.x), w6_, acc[1]); \
        acc[2] = fmaf(bf_lo(u_.y), w6_, acc[2]); \
        acc[3] = fmaf(bf_hi(u_.y), w6_, acc[3]); \
        acc[4] = fmaf(bf_lo(u_.z), w6_, acc[4]); \
        acc[5] = fmaf(bf_hi(u_.z), w6_, acc[5]); \
        acc[6] = fmaf(bf_lo(u_.w), w6_, acc[6]); \
        acc[7] = fmaf(bf_hi(u_.w), w6_, acc[7]); \
    } \
    _Pragma("unroll") \
    for (int rx = 0; rx < 6; ++rx) lhp[rx] = lhc_[rx]; }

__global__ __launch_bounds__(64) void attn_kernel(
    ushort16* qoh,
    const ushort16* __restrict__ kp, const ushort16* __restrict__ vp,
    const float* __restrict__ flow,
    float* __restrict__ attn)
{
    int blk = blockIdx.x;                        // 0..4095
    int swz = ((blk & 7) << 9) + (blk >> 3);     // XCD-contiguous pixel bands
    int tid = threadIdx.x;                       // 0..63
    int pix = swz * 4 + (tid >> 4);              // global pixel 0..16383
    int lg  = tid & 15;
    int c0  = lg * 8;
    int n   = pix >> 12;
    int yx  = pix & 4095;
    int y   = yx >> 6, x = yx & 63;

    float fx = flow[((size_t)n * 2 + 0) * HWp + yx];
    float fy = flow[((size_t)n * 2 + 1) * HWp + yx];
    float pxf = (float)x + fx, pyf = (float)y + fy;
    float X0 = floorf(pxf), Y0 = floorf(pyf);
    float wx = pxf - X0,    wy = pyf - Y0;
    int ix0 = (int)X0 - 2,  iy0 = (int)Y0 - 2;

    int coff[6], roff[6];
    float XA[6], XB[6], YT[6], YB[6];
#pragma unroll
    for (int r = 0; r < 6; ++r) {
        int xi = ix0 + r;
        float mx = (xi >= 0 && xi < WW) ? 1.f : 0.f;
        int xc = xi < 0 ? 0 : (xi > WW - 1 ? WW - 1 : xi);
        coff[r] = xc * CC;
        XA[r] = (1.f - wx) * mx;
        XB[r] = wx * mx;
        int yi = iy0 + r;
        float my = (yi >= 0 && yi < HH) ? 1.f : 0.f;
        int yc = yi < 0 ? 0 : (yi > HH - 1 ? HH - 1 : yi);
        roff[r] = yc * (WW * CC);
        YT[r] = (1.f - wy) * my;
        YB[r] = wy * my;
    }

    const ushort16* kb  = kp + (size_t)n * HWp * CC + c0;
    const ushort16* vbp = vp + (size_t)n * HWp * CC + c0;
    ushort16* qb = qoh + (size_t)pix * CC + c0;

    uint4 qraw = *reinterpret_cast<const uint4*>(qb);
    float qv[8] = { bf_lo(qraw.x), bf_hi(qraw.x), bf_lo(qraw.y), bf_hi(qraw.y),
                    bf_lo(qraw.z), bf_hi(qraw.z), bf_lo(qraw.w), bf_hi(qraw.w) };

    // ---- K pass: 2-buffer row pipeline ----
    float l[25];
    {
        uint4 kA[6], kB[6];
        KVLOAD(kA, kb, 0)
        KVLOAD(kB, kb, 1)
        KCONSUME(kA, 0)
        KVLOAD(kA, kb, 2)
        KCONSUME(kB, 1)
        KVLOAD(kB, kb, 3)
        KCONSUME(kA, 2)
        KVLOAD(kA, kb, 4)
        KCONSUME(kB, 3)
        KVLOAD(kB, kb, 5)
        KCONSUME(kA, 4)
        KCONSUME(kB, 5)
    }

    // ---- V prologue issued early: hides under reduce+softmax VALU ----
    uint4 vA[6], vB[6];
    KVLOAD(vA, vbp, 0)
    KVLOAD(vB, vbp, 1)

    // ---- reduce over 4 lanes (=32 ch) of this head ----
#pragma unroll
    for (int kk = 0; kk < 25; ++kk) {
        float s = l[kk];
        s += __shfl_xor(s, 1);
        s += __shfl_xor(s, 2);
        l[kk] = s * 0.17677669529663687f;   // 1/sqrt(32)
    }

    // ---- softmax over 25 ----
    float m = l[0];
#pragma unroll
    for (int kk = 1; kk < 25; ++kk) m = fmaxf(m, l[kk]);
    float sum = 0.f;
#pragma unroll
    for (int kk = 0; kk < 25; ++kk) { l[kk] = __expf(l[kk] - m); sum += l[kk]; }
    float inv = 1.f / sum;
#pragma unroll
    for (int kk = 0; kk < 25; ++kk) l[kk] *= inv;

    // ---- V pass: 2-buffer row pipeline ----
    float acc[8] = {0.f, 0.f, 0.f, 0.f, 0.f, 0.f, 0.f, 0.f};
    float lhp[6] = {0.f, 0.f, 0.f, 0.f, 0.f, 0.f};
    VCONSUME(vA, 0)
    KVLOAD(vA, vbp, 2)
    VCONSUME(vB, 1)
    KVLOAD(vB, vbp, 3)
    VCONSUME(vA, 2)
    KVLOAD(vA, vbp, 4)
    VCONSUME(vB, 3)
    KVLOAD(vB, vbp, 5)
    VCONSUME(vA, 4)
    VCONSUME(vB, 5)

    // ---- stores last: attn (fp32, reference layout) then oh in-place ----
    {
        int head = lg >> 2, j = lg & 3;
        float* ab = attn + (((size_t)n * NHEADS + head) * K2) * HWp + yx;
#pragma unroll
        for (int kk = 0; kk < 25; ++kk)
            if ((kk & 3) == j) ab[(size_t)kk * HWp] = l[kk];
    }

    uint4 o;
    o.x = pack2(acc[0], acc[1]);
    o.y = pack2(acc[2], acc[3]);
    o.z = pack2(acc[4], acc[5]);
    o.w = pack2(acc[6], acc[7]);
    *reinterpret_cast<uint4*>(qb) = o;     // oh, in-place over qp
}

// ---------------------------------------------------------------------------
// Kernel 3: MFMA final projection. out[o][pix] = Wfc * oh[pix][c]^T.
// ---------------------------------------------------------------------------
__global__ __launch_bounds__(256) void fc_mfma(
    const ushort16* __restrict__ oh, const ushort16* __restrict__ wfcb,
    float* __restrict__ out)
{
    int blk = blockIdx.x;
    int gp0 = blk * 64;
    int n   = gp0 >> 12;
    int yx0 = gp0 & 4095;

    int lane = threadIdx.x & 63;
    int wid  = threadIdx.x >> 6;
    int wr = wid >> 1, wc = wid & 1;
    int p16 = lane & 15, kg = lane >> 4;

    const ushort16* ohb = oh + (size_t)gp0 * CC;

    f32x4 acc[4][2] = {};

#pragma unroll
    for (int k0 = 0; k0 < 128; k0 += 32) {
        bf16x8 A[4], B[2];
#pragma unroll
        for (int ai = 0; ai < 4; ++ai) {
            int o = wr * 64 + ai * 16 + p16;
            A[ai] = *reinterpret_cast<const bf16x8*>(&wfcb[o * 128 + k0 + kg * 8]);
        }
#pragma unroll
        for (int bj = 0; bj < 2; ++bj) {
            int px = wc * 32 + bj * 16 + p16;
            B[bj] = *reinterpret_cast<const bf16x8*>(&ohb[(size_t)px * CC + k0 + kg * 8]);
        }
#pragma unroll
        for (int ai = 0; ai < 4; ++ai)
#pragma unroll
            for (int bj = 0; bj < 2; ++bj)
                acc[ai][bj] = __builtin_amdgcn_mfma_f32_16x16x32_bf16(
                    A[ai], B[bj], acc[ai][bj], 0, 0, 0);
    }

    float* ob = out + (size_t)n * CC * HWp + yx0;
#pragma unroll
    for (int ai = 0; ai < 4; ++ai) {
        int o = wr * 64 + ai * 16 + kg * 4;
#pragma unroll
        for (int bj = 0; bj < 2; ++bj) {
            int px = wc * 32 + bj * 16 + p16;
#pragma unroll
            for (int r = 0; r < 4; ++r)
                ob[(size_t)(o + r) * HWp + px] = acc[ai][bj][r];
        }
    }
}

// ---------------------------------------------------------------------------
extern "C" void kernel_launch(void* const* d_in, const int* in_sizes, int n_in,
                              void* d_out, int out_size, void* d_ws, size_t ws_size,
                              hipStream_t stream)
{
    const float* q    = (const float*)d_in[0];
    const float* k    = (const float*)d_in[1];
    const float* v    = (const float*)d_in[2];
    const float* flow = (const float*)d_in[3];
    const float* Wq   = (const float*)d_in[4];
    const float* Wk   = (const float*)d_in[5];
    const float* Wv   = (const float*)d_in[6];
    const float* Wfc  = (const float*)d_in[7];

    float* out  = (float*)d_out;                          // [N][C][H][W]
    float* attn = out + (size_t)NB * CC * HWp;            // [N][NHEADS][K2][H][W]

    ushort16* ws = (ushort16*)d_ws;
    size_t slab = (size_t)NB * HWp * CC;
    ushort16* qp  = ws;                                   // q -> oh in-place
    ushort16* kp  = ws + slab;
    ushort16* vp  = ws + 2 * slab;
    ushort16* wbf = ws + 3 * slab;

    wconv_kernel<<<dim3(64), dim3(256), 0, stream>>>(Wq, Wk, Wv, Wfc, wbf);
    proj_mfma<<<dim3(768), dim3(256), 0, stream>>>(q, k, v, wbf, qp, kp, vp);
    attn_kernel<<<dim3(4096), dim3(64), 0, stream>>>(qp, kp, vp, flow, attn);
    fc_mfma<<<dim3(256), dim3(256), 0, stream>>>(qp, wbf + 3 * 16384, out);
}